// Round 3
// baseline (595.311 us; speedup 1.0000x reference)
//
#include <hip/hip_runtime.h>

#define LOG2E 1.4426950408889634f

typedef __attribute__((ext_vector_type(8)))  __bf16       bf16x8;
typedef __attribute__((ext_vector_type(16))) float        f32x16;
typedef __attribute__((ext_vector_type(4)))  float        f32x4;
typedef __attribute__((ext_vector_type(4)))  unsigned int u32x4;

#define ROWPAT(g, hi) ((((g)&3)) + 8*((g)>>2) + 4*(hi))

__device__ inline unsigned short f2bf(float f){
  unsigned u = __builtin_bit_cast(unsigned, f);
  u += 0x7FFFu + ((u >> 16) & 1u);
  return (unsigned short)(u >> 16);
}
__device__ inline float bf2f(unsigned short h){
  unsigned u = ((unsigned)h) << 16;
  return __builtin_bit_cast(float, u);
}
__device__ inline unsigned pack2bf(float lo, float hi){
  return (unsigned)f2bf(lo) | ((unsigned)f2bf(hi) << 16);
}
__device__ inline f32x16 zero16(){
  f32x16 z;
  #pragma unroll
  for (int i=0;i<16;i++) z[i]=0.f;
  return z;
}

// ---------------- K0: W (512x512 fp32, [k][n]) -> Wt bf16 [n][k] ----------------
__global__ __launch_bounds__(256) void transpose_w_kernel(const float* __restrict__ W,
                                                          unsigned short* __restrict__ Wt){
  __shared__ unsigned short t[32][33];
  const int n0 = blockIdx.x*32, k0 = blockIdx.y*32;
  const int tx = threadIdx.x & 31, ty = threadIdx.x >> 5;   // ty 0..7
  #pragma unroll
  for (int i=0;i<4;i++){
    int k = ty*4 + i;
    t[k][tx] = f2bf(W[(size_t)(k0+k)*512 + n0+tx]);
  }
  __syncthreads();
  #pragma unroll
  for (int i=0;i<4;i++){
    int n = ty*4+i;
    Wt[(size_t)(n0+n)*512 + k0 + tx] = t[tx][n];
  }
}

// ---------------- K1: Y[b,h,l,dh] (bf16) = X(8192x512 fp32) @ W + bias ----------------
__global__ __launch_bounds__(256,2) void proj_gemm_kernel(
    const float* __restrict__ X, const unsigned int* __restrict__ Wt, // Wt: [n][k] as uint pairs [512][256]
    const float* __restrict__ bias, unsigned short* __restrict__ Y)
{
  __shared__ unsigned int Al[128][17];
  __shared__ unsigned int Bl[128][17];
  const int n0 = blockIdx.x * 128;
  const int m0 = blockIdx.y * 128;
  const int tid = threadIdx.x;
  const int lane = tid & 63, wave = tid >> 6;
  const int lr = lane & 31, hi = lane >> 5;
  const int wr = wave >> 1, wc = wave & 1;
  const int r = tid & 127, kh = tid >> 7;

  f32x16 acc[2][2];
  acc[0][0]=zero16(); acc[0][1]=zero16(); acc[1][0]=zero16(); acc[1][1]=zero16();

  for (int k0=0; k0<512; k0+=32){
    const float* Xr = X + (size_t)(m0 + r)*512 + k0 + kh*16;
    #pragma unroll
    for (int c=0;c<2;c++){
      f32x4 x0 = *(const f32x4*)(Xr + c*8);
      f32x4 x1 = *(const f32x4*)(Xr + c*8 + 4);
      Al[r][kh*8 + c*4 + 0] = pack2bf(x0[0], x0[1]);
      Al[r][kh*8 + c*4 + 1] = pack2bf(x0[2], x0[3]);
      Al[r][kh*8 + c*4 + 2] = pack2bf(x1[0], x1[1]);
      Al[r][kh*8 + c*4 + 3] = pack2bf(x1[2], x1[3]);
    }
    const unsigned int* Wr = Wt + (size_t)(n0 + r)*256 + (k0>>1) + kh*8;
    #pragma unroll
    for (int c=0;c<8;c++) Bl[r][kh*8 + c] = Wr[c];
    __syncthreads();
    #pragma unroll
    for (int t=0;t<2;t++){
      bf16x8 af[2], bfr[2];
      #pragma unroll
      for (int mt=0;mt<2;mt++){
        u32x4 w;
        #pragma unroll
        for (int j=0;j<4;j++) w[j] = Al[wr*64 + mt*32 + lr][t*8 + hi*4 + j];
        af[mt] = __builtin_bit_cast(bf16x8, w);
      }
      #pragma unroll
      for (int nt=0;nt<2;nt++){
        u32x4 w;
        #pragma unroll
        for (int j=0;j<4;j++) w[j] = Bl[wc*64 + nt*32 + lr][t*8 + hi*4 + j];
        bfr[nt] = __builtin_bit_cast(bf16x8, w);
      }
      #pragma unroll
      for (int mt=0;mt<2;mt++)
        #pragma unroll
        for (int nt=0;nt<2;nt++)
          acc[mt][nt] = __builtin_amdgcn_mfma_f32_32x32x16_bf16(af[mt], bfr[nt], acc[mt][nt], 0,0,0);
    }
    __syncthreads();
  }

  #pragma unroll
  for (int mt=0;mt<2;mt++)
    #pragma unroll
    for (int nt=0;nt<2;nt++){
      const int n = n0 + wc*64 + nt*32 + lr;
      const float bv = bias[n];
      const int h = n >> 6, dh = n & 63;
      #pragma unroll
      for (int g=0; g<16; g++){
        const int m = m0 + wr*64 + mt*32 + ROWPAT(g,hi);
        const int b = m >> 11, l = m & 2047;
        Y[((size_t)(b*8 + h)*2048 + l)*64 + dh] = f2bf(acc[mt][nt][g] + bv);
      }
    }
}

// ---------------- K2: fused relative attention ----------------
// grid (64 l-tiles, 32 bh), 512 threads (8 waves). One 32-row q-tile per block.
// Waves split the s-range; softmax stats and PV partials are merged across
// waves through LDS.
__global__ __launch_bounds__(512,2) void attn_kernel(
    const unsigned short* __restrict__ Q,
    const unsigned short* __restrict__ Kb,
    const unsigned short* __restrict__ Vb,
    const float* __restrict__ E,
    float* __restrict__ attn_w,
    unsigned short* __restrict__ attn_o)
{
  __shared__ unsigned short qe2[2048*32];   // 128 KiB: QE2^T[u][r] bf16; reused as fp32 reduce buf
  __shared__ float md_m[8][32];             // per-wave softmax max, per q-row
  __shared__ float md_d[8][32];             // per-wave softmax denom, per q-row
  const int l0 = blockIdx.x * 32;
  const int bh = blockIdx.y;
  const int tid = threadIdx.x;
  const int wave = tid >> 6;
  const int lane = tid & 63;
  const int lr = lane & 31;
  const int hi = lane >> 5;
  const int l  = l0 + lr;                   // this lane's q-row (col of swapped acc)

  // Q fragments (B operand of swapped QK): lane holds q-row l, d = 16t + 8hi + j
  const unsigned short* Qrow = Q + ((size_t)bh*2048 + l)*64;
  bf16x8 qf[4];
  #pragma unroll
  for (int t=0;t<4;t++) qf[t] = *(const bf16x8*)(Qrow + t*16 + hi*8);

  // Build QE2^T[u][r] = q_{l0+r} . E[2047-u]  (only u <= l0+31 needed)
  const int n_ut = (l0 >> 5) + 1;
  for (int ut = wave; ut < n_ut; ut += 8){
    const int u0 = ut*32;
    const float* Erow = E + (size_t)(2047 - (u0 + lr))*64;
    f32x16 acc = zero16();
    #pragma unroll
    for (int t=0;t<4;t++){
      f32x4 e0 = *(const f32x4*)(Erow + t*16 + hi*8);
      f32x4 e1 = *(const f32x4*)(Erow + t*16 + hi*8 + 4);
      u32x4 w;
      w[0]=pack2bf(e0[0],e0[1]); w[1]=pack2bf(e0[2],e0[3]);
      w[2]=pack2bf(e1[0],e1[1]); w[3]=pack2bf(e1[2],e1[3]);
      bf16x8 ef = __builtin_bit_cast(bf16x8, w);
      acc = __builtin_amdgcn_mfma_f32_32x32x16_bf16(ef, qf[t], acc, 0,0,0);
    }
    #pragma unroll
    for (int g=0; g<16; g++){
      int u = u0 + ROWPAT(g,hi);
      qe2[u*32 + lr] = f2bf(acc[g]);
    }
  }
  __syncthreads();

  const unsigned short* Krows = Kb + (size_t)bh*2048*64;
  const unsigned short* Vrows = Vb + (size_t)bh*2048*64;

  float m_run = -3e38f, d_run = 0.f;

  // ---- pass 1: per-wave online max + denominator over this wave's s-subset ----
  for (int it=0; it<8; it++){
    const int s0 = it*256 + wave*32;
    f32x16 acc = zero16();
    const unsigned short* Krow = Krows + (size_t)(s0 + lr)*64;
    #pragma unroll
    for (int t=0;t<4;t++){
      bf16x8 kf = *(const bf16x8*)(Krow + t*16 + hi*8);
      acc = __builtin_amdgcn_mfma_f32_32x32x16_bf16(kf, qf[t], acc, 0,0,0);
    }
    float lg[16];
    const bool anys = (s0 <= l0 + 31);
    #pragma unroll
    for (int g=0; g<16; g++){
      int s = s0 + ROWPAT(g,hi);
      float v = acc[g];
      if (anys && s <= l) v += bf2f(qe2[(l - s)*32 + lr]);
      lg[g] = v * 0.125f;
    }
    float mt = lg[0];
    #pragma unroll
    for (int g=1; g<16; g++) mt = fmaxf(mt, lg[g]);
    mt = fmaxf(mt, __shfl_xor(mt, 32, 64));
    float mnew = fmaxf(m_run, mt);
    float ps = 0.f;
    #pragma unroll
    for (int g=0; g<16; g++) ps += exp2f((lg[g]-mnew)*LOG2E);
    ps += __shfl_xor(ps, 32, 64);
    d_run = d_run * exp2f((m_run - mnew)*LOG2E) + ps;
    m_run = mnew;
  }

  // ---- cross-wave merge of softmax stats ----
  if (hi == 0){ md_m[wave][lr] = m_run; md_d[wave][lr] = d_run; }
  __syncthreads();
  float m_tot = md_m[0][lr];
  #pragma unroll
  for (int w=1; w<8; w++) m_tot = fmaxf(m_tot, md_m[w][lr]);
  float d_tot = 0.f;
  #pragma unroll
  for (int w=0; w<8; w++) d_tot += md_d[w][lr] * exp2f((md_m[w][lr] - m_tot)*LOG2E);
  m_run = m_tot;
  const float inv_d = 1.f / d_tot;

  // ---- pass 2: write attn_w + accumulate partial P.V ----
  f32x16 oacc[2];
  oacc[0]=zero16(); oacc[1]=zero16();
  float* awbase = attn_w + ((size_t)bh*2048 + l)*2048;

  for (int it=0; it<8; it++){
    const int s0 = it*256 + wave*32;
    f32x16 acc = zero16();
    const unsigned short* Krow = Krows + (size_t)(s0 + lr)*64;
    #pragma unroll
    for (int t=0;t<4;t++){
      bf16x8 kf = *(const bf16x8*)(Krow + t*16 + hi*8);
      acc = __builtin_amdgcn_mfma_f32_32x32x16_bf16(kf, qf[t], acc, 0,0,0);
    }
    const bool anys = (s0 <= l0 + 31);
    float p[16];
    #pragma unroll
    for (int g=0; g<16; g++){
      int s = s0 + ROWPAT(g,hi);
      float v = acc[g];
      if (anys && s <= l) v += bf2f(qe2[(l - s)*32 + lr]);
      p[g] = exp2f((v*0.125f - m_run)*LOG2E) * inv_d;
    }
    // store attn_w row chunks: regs 4q..4q+3 are s = s0 + 8q + 4hi + {0..3}
    #pragma unroll
    for (int q=0;q<4;q++){
      f32x4 st;
      #pragma unroll
      for (int j=0;j<4;j++) st[j] = p[q*4+j];
      __builtin_nontemporal_store(st, (f32x4*)(awbase + s0 + q*8 + hi*4));
    }
    // pack P to bf16 pairs; pk[i] holds s-rows (8*(i>>1)+2*(i&1)+4hi, +1) for col l
    unsigned pk[8], sw[8];
    #pragma unroll
    for (int i=0;i<8;i++) pk[i] = pack2bf(p[i*2], p[i*2+1]);
    #pragma unroll
    for (int i=0;i<8;i++) sw[i] = (unsigned)__shfl_xor((int)pk[i], 32, 64);
    #pragma unroll
    for (int t=0;t<2;t++){
      u32x4 w;
      w[0] = hi ? sw[4*t+2] : pk[4*t];
      w[1] = hi ? sw[4*t+3] : pk[4*t+1];
      w[2] = hi ? pk[4*t+2] : sw[4*t];
      w[3] = hi ? pk[4*t+3] : sw[4*t+1];
      bf16x8 pa = __builtin_bit_cast(bf16x8, w);
      #pragma unroll
      for (int dt=0; dt<2; dt++){
        const unsigned short* Vcol = Vrows + (size_t)(s0 + t*16 + hi*8)*64 + dt*32 + lr;
        u32x4 vw;
        #pragma unroll
        for (int j2=0; j2<4; j2++)
          vw[j2] = (unsigned)Vcol[(size_t)(2*j2)*64] | ((unsigned)Vcol[(size_t)(2*j2+1)*64] << 16);
        bf16x8 vfr = __builtin_bit_cast(bf16x8, vw);
        oacc[dt] = __builtin_amdgcn_mfma_f32_32x32x16_bf16(pa, vfr, oacc[dt], 0,0,0);
      }
    }
  }

  // ---- cross-wave reduce of PV partials ----
  __syncthreads();                    // qe2 now dead; reuse as fp32 buffer
  float* fbuf = (float*)qe2;          // [8 waves][32 rows][64 cols]
  #pragma unroll
  for (int dt=0; dt<2; dt++)
    #pragma unroll
    for (int g=0; g<16; g++){
      int row = ROWPAT(g,hi);
      fbuf[wave*2048 + row*64 + dt*32 + lr] = oacc[dt][g];
    }
  __syncthreads();
  unsigned short* Obase = attn_o + ((size_t)bh*2048 + l0)*64;
  for (int o = tid; o < 2048; o += 512){
    float s = 0.f;
    #pragma unroll
    for (int w=0; w<8; w++) s += fbuf[w*2048 + o];
    Obase[o] = f2bf(s);
  }
}

// ---------------- K3: out(8192x512 fp32) = attn_gathered(bf16) @ fc_w + fc_b ----------------
__global__ __launch_bounds__(256,2) void fc_gemm_kernel(
    const unsigned short* __restrict__ A,   // [b,h,l,dh] bf16
    const unsigned int* __restrict__ Wt,    // fc_w^T [n][k] as uint pairs
    const float* __restrict__ bias, float* __restrict__ Out)
{
  __shared__ unsigned int Al[128][17];
  __shared__ unsigned int Bl[128][17];
  const int n0 = blockIdx.x * 128;
  const int m0 = blockIdx.y * 128;
  const int tid = threadIdx.x;
  const int lane = tid & 63, wave = tid >> 6;
  const int lr = lane & 31, hi = lane >> 5;
  const int wr = wave >> 1, wc = wave & 1;
  const int r = tid & 127, kh = tid >> 7;

  f32x16 acc[2][2];
  acc[0][0]=zero16(); acc[0][1]=zero16(); acc[1][0]=zero16(); acc[1][1]=zero16();

  for (int k0=0; k0<512; k0+=32){
    const int m = m0 + r; const int b = m >> 11, l = m & 2047;
    const int k = k0 + kh*16; const int h = k >> 6, dh0 = k & 63;
    const unsigned int* Ar = (const unsigned int*)(A + ((size_t)(b*8+h)*2048 + l)*64 + dh0);
    #pragma unroll
    for (int c=0;c<8;c++) Al[r][kh*8+c] = Ar[c];
    const unsigned int* Wr = Wt + (size_t)(n0 + r)*256 + (k0>>1) + kh*8;
    #pragma unroll
    for (int c=0;c<8;c++) Bl[r][kh*8 + c] = Wr[c];
    __syncthreads();
    #pragma unroll
    for (int t=0;t<2;t++){
      bf16x8 af[2], bfr[2];
      #pragma unroll
      for (int mt=0;mt<2;mt++){
        u32x4 w;
        #pragma unroll
        for (int j=0;j<4;j++) w[j] = Al[wr*64 + mt*32 + lr][t*8 + hi*4 + j];
        af[mt] = __builtin_bit_cast(bf16x8, w);
      }
      #pragma unroll
      for (int nt=0;nt<2;nt++){
        u32x4 w;
        #pragma unroll
        for (int j=0;j<4;j++) w[j] = Bl[wc*64 + nt*32 + lr][t*8 + hi*4 + j];
        bfr[nt] = __builtin_bit_cast(bf16x8, w);
      }
      #pragma unroll
      for (int mt=0;mt<2;mt++)
        #pragma unroll
        for (int nt=0;nt<2;nt++)
          acc[mt][nt] = __builtin_amdgcn_mfma_f32_32x32x16_bf16(af[mt], bfr[nt], acc[mt][nt], 0,0,0);
    }
    __syncthreads();
  }

  #pragma unroll
  for (int mt=0;mt<2;mt++)
    #pragma unroll
    for (int nt=0;nt<2;nt++){
      const int n = n0 + wc*64 + nt*32 + lr;
      const float bv = bias[n];
      #pragma unroll
      for (int g=0; g<16; g++){
        const int m2 = m0 + wr*64 + mt*32 + ROWPAT(g,hi);
        Out[(size_t)m2*512 + n] = acc[mt][nt][g] + bv;
      }
    }
}

extern "C" void kernel_launch(void* const* d_in, const int* in_sizes, int n_in,
                              void* d_out, int out_size, void* d_ws, size_t ws_size,
                              hipStream_t stream)
{
  const float* q_in = (const float*)d_in[0];
  const float* k_in = (const float*)d_in[1];
  const float* v_in = (const float*)d_in[2];
  const float* Wq_w = (const float*)d_in[3];
  const float* Wq_b = (const float*)d_in[4];
  const float* Wk_w = (const float*)d_in[5];
  const float* Wk_b = (const float*)d_in[6];
  const float* Wv_w = (const float*)d_in[7];
  const float* Wv_b = (const float*)d_in[8];
  const float* E    = (const float*)d_in[9];
  const float* fc_w = (const float*)d_in[10];
  const float* fc_b = (const float*)d_in[11];

  float* out = (float*)d_out;
  float* attn_w = out + (size_t)4*2048*512;

  unsigned short* Qws = (unsigned short*)d_ws;          // B*H*L*DH = 4194304 elems each
  unsigned short* Kws = Qws + (size_t)4194304;
  unsigned short* Vws = Kws + (size_t)4194304;
  unsigned short* ATT = Vws + (size_t)4194304;
  unsigned short* WqT = ATT + (size_t)4194304;
  unsigned short* WkT = WqT + 262144;
  unsigned short* WvT = WkT + 262144;
  unsigned short* WfT = WvT + 262144;

  dim3 tg(16,16);
  hipLaunchKernelGGL(transpose_w_kernel, tg, dim3(256), 0, stream, Wq_w, WqT);
  hipLaunchKernelGGL(transpose_w_kernel, tg, dim3(256), 0, stream, Wk_w, WkT);
  hipLaunchKernelGGL(transpose_w_kernel, tg, dim3(256), 0, stream, Wv_w, WvT);
  hipLaunchKernelGGL(transpose_w_kernel, tg, dim3(256), 0, stream, fc_w, WfT);

  dim3 pg(4, 64);
  hipLaunchKernelGGL(proj_gemm_kernel, pg, dim3(256), 0, stream, q_in, (const unsigned int*)WqT, Wq_b, Qws);
  hipLaunchKernelGGL(proj_gemm_kernel, pg, dim3(256), 0, stream, k_in, (const unsigned int*)WkT, Wk_b, Kws);
  hipLaunchKernelGGL(proj_gemm_kernel, pg, dim3(256), 0, stream, v_in, (const unsigned int*)WvT, Wv_b, Vws);

  hipLaunchKernelGGL(attn_kernel, dim3(64,32), dim3(512), 0, stream, Qws, Kws, Vws, E, attn_w, ATT);

  hipLaunchKernelGGL(fc_gemm_kernel, pg, dim3(256), 0, stream, ATT, (const unsigned int*)WfT, fc_b, out);
}